// Round 1
// baseline (2402.952 us; speedup 1.0000x reference)
//
#include <hip/hip_runtime.h>
#include <math.h>

#define HID 16

// ---------------------------------------------------------------------------
// CSR build: count in-degrees, prefix-sum, scatter src ids into dst-sorted col
// ---------------------------------------------------------------------------

__global__ void count_deg(const int* __restrict__ dst, int* __restrict__ cnt, int E) {
    int e = blockIdx.x * blockDim.x + threadIdx.x;
    if (e < E) atomicAdd(&cnt[dst[e]], 1);
}

// Single-block scan over N counts -> row_ptr/cursor; also derive w=1/deg, dinv=deg^-1/2
__global__ void scan_build(const int* __restrict__ cnt, int* __restrict__ row_ptr,
                           int* __restrict__ cursor, float* __restrict__ w,
                           float* __restrict__ dinv, int N) {
    __shared__ int sums[1024];
    int t = threadIdx.x;
    int C = (N + 1023) >> 10;
    int b = t * C;
    int e = min(b + C, N);
    int s = 0;
    for (int i = b; i < e; ++i) s += cnt[i];
    sums[t] = s;
    __syncthreads();
    if (t == 0) {
        int run = 0;
        for (int i = 0; i < 1024; ++i) { int v = sums[i]; sums[i] = run; run += v; }
        row_ptr[N] = run;   // == E
    }
    __syncthreads();
    int off = sums[t];
    for (int i = b; i < e; ++i) {
        int c = cnt[i];
        row_ptr[i] = off;
        cursor[i]  = off;
        float deg = (float)(c + 1);          // +1 self-loop
        w[i]    = 1.0f / deg;
        dinv[i] = 1.0f / sqrtf(deg);
        off += c;
    }
}

__global__ void fill_csr(const int* __restrict__ src, const int* __restrict__ dst,
                         int* __restrict__ cursor, int* __restrict__ col, int E) {
    int e = blockIdx.x * blockDim.x + threadIdx.x;
    if (e < E) {
        int d = dst[e];
        int p = atomicAdd(&cursor[d], 1);
        col[p] = src[e];
    }
}

// ---------------------------------------------------------------------------
// MLP encoder: h0 = relu(relu(x*W1+b1) @ W2 + b2); store g0 = dinv * h0
// ---------------------------------------------------------------------------
__global__ void encoder(const float* __restrict__ x, const float* __restrict__ W1,
                        const float* __restrict__ b1, const float* __restrict__ W2,
                        const float* __restrict__ b2, const float* __restrict__ dinv,
                        float* __restrict__ g0, int N) {
    int v = blockIdx.x * blockDim.x + threadIdx.x;
    if (v >= N) return;
    float xv = x[v];
    float h1[HID];
#pragma unroll
    for (int j = 0; j < HID; ++j) h1[j] = fmaxf(xv * W1[j] + b1[j], 0.0f);
    float dv = dinv[v];
#pragma unroll
    for (int j = 0; j < HID; ++j) {
        float s = b2[j];
#pragma unroll
        for (int i = 0; i < HID; ++i) s += h1[i] * W2[i * HID + j];
        g0[v * HID + j] = dv * fmaxf(s, 0.0f);
    }
}

// ---------------------------------------------------------------------------
// One APPNP round on g: g_out[v] = 0.9*w[v]*(sum_in g_in[src] + g_in[v]) + 0.1*g0[v]
// 16 lanes per node (lane j owns hidden dim j); col[k] load broadcasts across lanes.
// ---------------------------------------------------------------------------
__global__ void prop(const float* __restrict__ gin, const float* __restrict__ g0,
                     const int* __restrict__ row_ptr, const int* __restrict__ col,
                     const float* __restrict__ w, float* __restrict__ gout, int N) {
    int gid = blockIdx.x * blockDim.x + threadIdx.x;
    int v = gid >> 4;
    int j = gid & 15;
    if (v >= N) return;
    int s = row_ptr[v];
    int e = row_ptr[v + 1];
    float acc = gin[v * HID + j];            // self-loop term
    for (int k = s; k < e; ++k) {
        acc += gin[col[k] * HID + j];
    }
    gout[v * HID + j] = 0.9f * w[v] * acc + 0.1f * g0[v * HID + j];
}

// ---------------------------------------------------------------------------
// Head: y[v] = (g_K[v]/dinv[v]) . W3 + b3
// ---------------------------------------------------------------------------
__global__ void out_head(const float* __restrict__ g, const float* __restrict__ W3,
                         const float* __restrict__ b3, const float* __restrict__ dinv,
                         float* __restrict__ y, int N) {
    int v = blockIdx.x * blockDim.x + threadIdx.x;
    if (v >= N) return;
    float s = 0.0f;
#pragma unroll
    for (int j = 0; j < HID; ++j) s += g[v * HID + j] * W3[j];
    y[v] = s / dinv[v] + b3[0];
}

extern "C" void kernel_launch(void* const* d_in, const int* in_sizes, int n_in,
                              void* d_out, int out_size, void* d_ws, size_t ws_size,
                              hipStream_t stream) {
    const float* x  = (const float*)d_in[0];
    const int* edge = (const int*)d_in[1];   // int64 in ref -> int32 from harness
    const float* W1 = (const float*)d_in[2];
    const float* b1 = (const float*)d_in[3];
    const float* W2 = (const float*)d_in[4];
    const float* b2 = (const float*)d_in[5];
    const float* W3 = (const float*)d_in[6];
    const float* b3 = (const float*)d_in[7];
    float* y = (float*)d_out;

    const int N = in_sizes[0];       // 100000
    const int E = in_sizes[1] / 2;   // 5000000
    const int* src = edge;
    const int* dst = edge + E;

    char* ws = (char*)d_ws;
    size_t off = 0;
    auto alloc = [&](size_t bytes) -> void* {
        void* p = ws + off;
        off += (bytes + 255) & ~(size_t)255;
        return p;
    };

    int*   cnt     = (int*)  alloc((size_t)N * 4);
    int*   row_ptr = (int*)  alloc((size_t)(N + 1) * 4);
    int*   cursor  = (int*)  alloc((size_t)N * 4);
    int*   col     = (int*)  alloc((size_t)E * 4);
    float* w       = (float*)alloc((size_t)N * 4);
    float* dinv    = (float*)alloc((size_t)N * 4);
    float* g0      = (float*)alloc((size_t)N * HID * 4);
    float* gB      = (float*)alloc((size_t)N * HID * 4);
    float* gC      = (float*)alloc((size_t)N * HID * 4);

    hipMemsetAsync(cnt, 0, (size_t)N * 4, stream);

    count_deg<<<(E + 255) / 256, 256, 0, stream>>>(dst, cnt, E);
    scan_build<<<1, 1024, 0, stream>>>(cnt, row_ptr, cursor, w, dinv, N);
    fill_csr<<<(E + 255) / 256, 256, 0, stream>>>(src, dst, cursor, col, E);
    encoder<<<(N + 255) / 256, 256, 0, stream>>>(x, W1, b1, W2, b2, dinv, g0, N);

    const float* gin = g0;
    float* gout = gB;
    for (int k = 0; k < 10; ++k) {
        prop<<<((N * HID) + 255) / 256, 256, 0, stream>>>(gin, g0, row_ptr, col, w, gout, N);
        gin = gout;
        gout = (gout == gB) ? gC : gB;
    }

    out_head<<<(N + 255) / 256, 256, 0, stream>>>(gin, W3, b3, dinv, y, N);
}

// Round 2
// 1868.638 us; speedup vs baseline: 1.2859x; 1.2859x over previous
//
#include <hip/hip_runtime.h>
#include <math.h>

#define HID 16

// ---------------------------------------------------------------------------
// CSR build: count in-degrees, prefix-sum, scatter src ids into dst-sorted col
// ---------------------------------------------------------------------------

__global__ void count_deg(const int* __restrict__ dst, int* __restrict__ cnt, int E) {
    int e = blockIdx.x * blockDim.x + threadIdx.x;
    if (e < E) atomicAdd(&cnt[dst[e]], 1);
}

// Single-block scan over N counts -> row_ptr/cursor; also derive w=1/deg, dinv=deg^-1/2
__global__ void scan_build(const int* __restrict__ cnt, int* __restrict__ row_ptr,
                           int* __restrict__ cursor, float* __restrict__ w,
                           float* __restrict__ dinv, int N) {
    __shared__ int sums[1024];
    int t = threadIdx.x;
    int C = (N + 1023) >> 10;
    int b = t * C;
    int e = min(b + C, N);
    int s = 0;
    for (int i = b; i < e; ++i) s += cnt[i];
    sums[t] = s;
    __syncthreads();
    if (t == 0) {
        int run = 0;
        for (int i = 0; i < 1024; ++i) { int v = sums[i]; sums[i] = run; run += v; }
        row_ptr[N] = run;   // == E
    }
    __syncthreads();
    int off = sums[t];
    for (int i = b; i < e; ++i) {
        int c = cnt[i];
        row_ptr[i] = off;
        cursor[i]  = off;
        float deg = (float)(c + 1);          // +1 self-loop
        w[i]    = 1.0f / deg;
        dinv[i] = 1.0f / sqrtf(deg);
        off += c;
    }
}

__global__ void fill_csr(const int* __restrict__ src, const int* __restrict__ dst,
                         int* __restrict__ cursor, int* __restrict__ col, int E) {
    int e = blockIdx.x * blockDim.x + threadIdx.x;
    if (e < E) {
        int d = dst[e];
        int p = atomicAdd(&cursor[d], 1);
        col[p] = src[e];
    }
}

// ---------------------------------------------------------------------------
// MLP encoder: h0 = relu(relu(x*W1+b1) @ W2 + b2); store g0 = dinv * h0
// ---------------------------------------------------------------------------
__global__ void encoder(const float* __restrict__ x, const float* __restrict__ W1,
                        const float* __restrict__ b1, const float* __restrict__ W2,
                        const float* __restrict__ b2, const float* __restrict__ dinv,
                        float* __restrict__ g0, int N) {
    int v = blockIdx.x * blockDim.x + threadIdx.x;
    if (v >= N) return;
    float xv = x[v];
    float h1[HID];
#pragma unroll
    for (int j = 0; j < HID; ++j) h1[j] = fmaxf(xv * W1[j] + b1[j], 0.0f);
    float dv = dinv[v];
#pragma unroll
    for (int j = 0; j < HID; ++j) {
        float s = b2[j];
#pragma unroll
        for (int i = 0; i < HID; ++i) s += h1[i] * W2[i * HID + j];
        g0[v * HID + j] = dv * fmaxf(s, 0.0f);
    }
}

// ---------------------------------------------------------------------------
// One APPNP round: g_out[v] = 0.9*w[v]*(sum_in g_in[src] + g_in[v]) + 0.1*g0[v]
// One wave (64 lanes) per node: 4 sub-groups of 16 lanes walk strided quarters
// of the edge list (x2 manual unroll -> 8 independent gather chains per wave),
// then butterfly-reduce across sub-groups; sub 0 writes the 64B node row.
// ---------------------------------------------------------------------------
__global__ void prop(const float* __restrict__ gin, const float* __restrict__ g0,
                     const int* __restrict__ row_ptr, const int* __restrict__ col,
                     const float* __restrict__ w, float* __restrict__ gout, int N) {
    int gid = blockIdx.x * blockDim.x + threadIdx.x;
    int v = gid >> 6;                    // one wave per node
    if (v >= N) return;
    int lane = threadIdx.x & 63;
    int sub = lane >> 4;                 // 0..3 edge sub-group
    int j = lane & 15;                   // hidden dim

    int s = row_ptr[v];
    int e = row_ptr[v + 1];

    float acc = (sub == 0) ? gin[v * HID + j] : 0.0f;   // self-loop term

    int k = s + sub;
    for (; k + 4 < e; k += 8) {
        int c0 = col[k];
        int c1 = col[k + 4];
        float a0 = gin[c0 * HID + j];
        float a1 = gin[c1 * HID + j];
        acc += a0;
        acc += a1;
    }
    if (k < e) acc += gin[col[k] * HID + j];

    // reduce the 4 sub-group partials (lanes j, j+16, j+32, j+48)
    acc += __shfl_xor(acc, 16);
    acc += __shfl_xor(acc, 32);

    if (sub == 0) {
        gout[v * HID + j] = 0.9f * w[v] * acc + 0.1f * g0[v * HID + j];
    }
}

// ---------------------------------------------------------------------------
// Head: y[v] = (g_K[v]/dinv[v]) . W3 + b3
// ---------------------------------------------------------------------------
__global__ void out_head(const float* __restrict__ g, const float* __restrict__ W3,
                         const float* __restrict__ b3, const float* __restrict__ dinv,
                         float* __restrict__ y, int N) {
    int v = blockIdx.x * blockDim.x + threadIdx.x;
    if (v >= N) return;
    float s = 0.0f;
#pragma unroll
    for (int j = 0; j < HID; ++j) s += g[v * HID + j] * W3[j];
    y[v] = s / dinv[v] + b3[0];
}

extern "C" void kernel_launch(void* const* d_in, const int* in_sizes, int n_in,
                              void* d_out, int out_size, void* d_ws, size_t ws_size,
                              hipStream_t stream) {
    const float* x  = (const float*)d_in[0];
    const int* edge = (const int*)d_in[1];
    const float* W1 = (const float*)d_in[2];
    const float* b1 = (const float*)d_in[3];
    const float* W2 = (const float*)d_in[4];
    const float* b2 = (const float*)d_in[5];
    const float* W3 = (const float*)d_in[6];
    const float* b3 = (const float*)d_in[7];
    float* y = (float*)d_out;

    const int N = in_sizes[0];       // 100000
    const int E = in_sizes[1] / 2;   // 5000000
    const int* src = edge;
    const int* dst = edge + E;

    char* ws = (char*)d_ws;
    size_t off = 0;
    auto alloc = [&](size_t bytes) -> void* {
        void* p = ws + off;
        off += (bytes + 255) & ~(size_t)255;
        return p;
    };

    int*   cnt     = (int*)  alloc((size_t)N * 4);
    int*   row_ptr = (int*)  alloc((size_t)(N + 1) * 4);
    int*   cursor  = (int*)  alloc((size_t)N * 4);
    int*   col     = (int*)  alloc((size_t)E * 4);
    float* w       = (float*)alloc((size_t)N * 4);
    float* dinv    = (float*)alloc((size_t)N * 4);
    float* g0      = (float*)alloc((size_t)N * HID * 4);
    float* gB      = (float*)alloc((size_t)N * HID * 4);
    float* gC      = (float*)alloc((size_t)N * HID * 4);

    hipMemsetAsync(cnt, 0, (size_t)N * 4, stream);

    count_deg<<<(E + 255) / 256, 256, 0, stream>>>(dst, cnt, E);
    scan_build<<<1, 1024, 0, stream>>>(cnt, row_ptr, cursor, w, dinv, N);
    fill_csr<<<(E + 255) / 256, 256, 0, stream>>>(src, dst, cursor, col, E);
    encoder<<<(N + 255) / 256, 256, 0, stream>>>(x, W1, b1, W2, b2, dinv, g0, N);

    const float* gin = g0;
    float* gout = gB;
    for (int k = 0; k < 10; ++k) {
        // one wave (64 threads) per node
        long long total = (long long)N * 64;
        prop<<<(int)((total + 255) / 256), 256, 0, stream>>>(gin, g0, row_ptr, col, w, gout, N);
        gin = gout;
        gout = (gout == gB) ? gC : gB;
    }

    out_head<<<(N + 255) / 256, 256, 0, stream>>>(gin, W3, b3, dinv, y, N);
}

// Round 3
// 1419.281 us; speedup vs baseline: 1.6931x; 1.3166x over previous
//
#include <hip/hip_runtime.h>
#include <math.h>

#define HID 16
#define RANGES 8

// ---------------------------------------------------------------------------
// CSR build: count in-degrees, prefix-sum, scatter src ids into dst-sorted col
// ---------------------------------------------------------------------------

__global__ void count_deg(const int* __restrict__ dst, int* __restrict__ cnt, int E) {
    int e = blockIdx.x * blockDim.x + threadIdx.x;
    if (e < E) atomicAdd(&cnt[dst[e]], 1);
}

// Single-block scan over N counts -> row_ptr/cursor; also derive w=1/deg, dinv=deg^-1/2
__global__ void scan_build(const int* __restrict__ cnt, int* __restrict__ row_ptr,
                           int* __restrict__ cursor, float* __restrict__ w,
                           float* __restrict__ dinv, int N) {
    __shared__ int sums[1024];
    int t = threadIdx.x;
    int C = (N + 1023) >> 10;
    int b = t * C;
    int e = min(b + C, N);
    int s = 0;
    for (int i = b; i < e; ++i) s += cnt[i];
    sums[t] = s;
    __syncthreads();
    if (t == 0) {
        int run = 0;
        for (int i = 0; i < 1024; ++i) { int v = sums[i]; sums[i] = run; run += v; }
        row_ptr[N] = run;   // == E
    }
    __syncthreads();
    int off = sums[t];
    for (int i = b; i < e; ++i) {
        int c = cnt[i];
        row_ptr[i] = off;
        cursor[i]  = off;
        float deg = (float)(c + 1);          // +1 self-loop
        w[i]    = 1.0f / deg;
        dinv[i] = 1.0f / sqrtf(deg);
        off += c;
    }
}

// Range-filtered scatter: blockIdx%8 selects a dst range (~12.5K nodes, 2.5MB of
// col). Round-robin workgroup->XCD dispatch means each col window is written by
// (mostly) one XCD -> lines complete in its L2 -> ~20MB writeback instead of 300MB.
// Edges are re-read 8x but are L3-resident (NT loads keep them out of L2).
__global__ void fill_csr(const int* __restrict__ src, const int* __restrict__ dst,
                         int* __restrict__ cursor, int* __restrict__ col,
                         int E, int range_step, int N) {
    int r = blockIdx.x & (RANGES - 1);
    int chunk = blockIdx.x >> 3;
    int nchunks = gridDim.x >> 3;
    int lo = r * range_step;
    int hi = min(lo + range_step, N);
    int stride = nchunks * blockDim.x;
    for (int e = chunk * blockDim.x + threadIdx.x; e < E; e += stride) {
        int d = __builtin_nontemporal_load(dst + e);
        if (d >= lo && d < hi) {
            int sv = __builtin_nontemporal_load(src + e);
            int p = atomicAdd(&cursor[d], 1);
            col[p] = sv;
        }
    }
}

// ---------------------------------------------------------------------------
// MLP encoder: h0 = relu(relu(x*W1+b1) @ W2 + b2); store g0 = dinv * h0
// ---------------------------------------------------------------------------
__global__ void encoder(const float* __restrict__ x, const float* __restrict__ W1,
                        const float* __restrict__ b1, const float* __restrict__ W2,
                        const float* __restrict__ b2, const float* __restrict__ dinv,
                        float* __restrict__ g0, int N) {
    int v = blockIdx.x * blockDim.x + threadIdx.x;
    if (v >= N) return;
    float xv = x[v];
    float h1[HID];
#pragma unroll
    for (int j = 0; j < HID; ++j) h1[j] = fmaxf(xv * W1[j] + b1[j], 0.0f);
    float dv = dinv[v];
#pragma unroll
    for (int j = 0; j < HID; ++j) {
        float s = b2[j];
#pragma unroll
        for (int i = 0; i < HID; ++i) s += h1[i] * W2[i * HID + j];
        g0[v * HID + j] = dv * fmaxf(s, 0.0f);
    }
}

// ---------------------------------------------------------------------------
// One APPNP round: g_out[v] = 0.9*w[v]*(sum_in g_in[src] + g_in[v]) + 0.1*g0[v]
// 16 lanes per node (lane j owns dim j). The 16-lane group vector-loads 16 col
// entries (one coalesced NT 64B read), shfl-broadcasts each src id, and issues
// 16 independent row-gathers (64B coalesced lines) -> 16 lines in flight per
// subgroup, 64 per wave.
// ---------------------------------------------------------------------------
__global__ void prop(const float* __restrict__ gin, const float* __restrict__ g0,
                     const int* __restrict__ row_ptr, const int* __restrict__ col,
                     const float* __restrict__ w, float* __restrict__ gout, int N) {
    int gid = blockIdx.x * blockDim.x + threadIdx.x;
    int v = gid >> 4;
    if (v >= N) return;
    int j = threadIdx.x & 15;

    int s = row_ptr[v];
    int e = row_ptr[v + 1];

    float acc = gin[v * HID + j];            // self-loop term

    int k = s;
    for (; k + 16 <= e; k += 16) {
        int cv = __builtin_nontemporal_load(col + k + j);
#pragma unroll
        for (int i = 0; i < 16; ++i) {
            int c = __shfl(cv, i, 16);
            acc += gin[c * HID + j];
        }
    }
    // tail: rem < 16 edges
    int rem = e - k;
    int cvt = 0;
    if (j < rem) cvt = __builtin_nontemporal_load(col + k + j);
    for (int i = 0; i < rem; ++i) {
        int c = __shfl(cvt, i, 16);
        acc += gin[c * HID + j];
    }

    gout[v * HID + j] = 0.9f * w[v] * acc + 0.1f * g0[v * HID + j];
}

// ---------------------------------------------------------------------------
// Head: y[v] = (g_K[v]/dinv[v]) . W3 + b3
// ---------------------------------------------------------------------------
__global__ void out_head(const float* __restrict__ g, const float* __restrict__ W3,
                         const float* __restrict__ b3, const float* __restrict__ dinv,
                         float* __restrict__ y, int N) {
    int v = blockIdx.x * blockDim.x + threadIdx.x;
    if (v >= N) return;
    float s = 0.0f;
#pragma unroll
    for (int j = 0; j < HID; ++j) s += g[v * HID + j] * W3[j];
    y[v] = s / dinv[v] + b3[0];
}

extern "C" void kernel_launch(void* const* d_in, const int* in_sizes, int n_in,
                              void* d_out, int out_size, void* d_ws, size_t ws_size,
                              hipStream_t stream) {
    const float* x  = (const float*)d_in[0];
    const int* edge = (const int*)d_in[1];
    const float* W1 = (const float*)d_in[2];
    const float* b1 = (const float*)d_in[3];
    const float* W2 = (const float*)d_in[4];
    const float* b2 = (const float*)d_in[5];
    const float* W3 = (const float*)d_in[6];
    const float* b3 = (const float*)d_in[7];
    float* y = (float*)d_out;

    const int N = in_sizes[0];       // 100000
    const int E = in_sizes[1] / 2;   // 5000000
    const int* src = edge;
    const int* dst = edge + E;

    char* ws = (char*)d_ws;
    size_t off = 0;
    auto alloc = [&](size_t bytes) -> void* {
        void* p = ws + off;
        off += (bytes + 255) & ~(size_t)255;
        return p;
    };

    int*   cnt     = (int*)  alloc((size_t)N * 4);
    int*   row_ptr = (int*)  alloc((size_t)(N + 1) * 4);
    int*   cursor  = (int*)  alloc((size_t)N * 4);
    int*   col     = (int*)  alloc((size_t)E * 4);
    float* w       = (float*)alloc((size_t)N * 4);
    float* dinv    = (float*)alloc((size_t)N * 4);
    float* g0      = (float*)alloc((size_t)N * HID * 4);
    float* gB      = (float*)alloc((size_t)N * HID * 4);
    float* gC      = (float*)alloc((size_t)N * HID * 4);

    hipMemsetAsync(cnt, 0, (size_t)N * 4, stream);

    count_deg<<<(E + 255) / 256, 256, 0, stream>>>(dst, cnt, E);
    scan_build<<<1, 1024, 0, stream>>>(cnt, row_ptr, cursor, w, dinv, N);

    // 2048 blocks = 8 ranges x 256 edge-chunks; blockIdx%8 -> XCD round-robin
    int range_step = (N + RANGES - 1) / RANGES;
    fill_csr<<<2048, 256, 0, stream>>>(src, dst, cursor, col, E, range_step, N);

    encoder<<<(N + 255) / 256, 256, 0, stream>>>(x, W1, b1, W2, b2, dinv, g0, N);

    const float* gin = g0;
    float* gout = gB;
    for (int k = 0; k < 10; ++k) {
        long long total = (long long)N * 16;   // 16 lanes per node
        prop<<<(int)((total + 255) / 256), 256, 0, stream>>>(gin, g0, row_ptr, col, w, gout, N);
        gin = gout;
        gout = (gout == gB) ? gC : gB;
    }

    out_head<<<(N + 255) / 256, 256, 0, stream>>>(gin, W3, b3, dinv, y, N);
}

// Round 4
// 1098.692 us; speedup vs baseline: 2.1871x; 1.2918x over previous
//
#include <hip/hip_runtime.h>
#include <math.h>

#define HID 16
#define RANGES 8

// ---------------------------------------------------------------------------
// CSR build: count in-degrees, hierarchical prefix-sum, range-filtered scatter
// ---------------------------------------------------------------------------

__global__ void count_deg(const int* __restrict__ dst, int* __restrict__ cnt, int E) {
    int e = blockIdx.x * blockDim.x + threadIdx.x;
    if (e < E) atomicAdd(&cnt[dst[e]], 1);
}

// Stage 1: per-block (256 counts) sum -> bsum[block]
__global__ void block_reduce(const int* __restrict__ cnt, int* __restrict__ bsum, int N) {
    int i = blockIdx.x * blockDim.x + threadIdx.x;
    int v = (i < N) ? cnt[i] : 0;
#pragma unroll
    for (int o = 1; o < 64; o <<= 1) v += __shfl_xor(v, o);
    __shared__ int ws[4];
    int lane = threadIdx.x & 63;
    int wid = threadIdx.x >> 6;
    if (lane == 0) ws[wid] = v;
    __syncthreads();
    if (threadIdx.x == 0) bsum[blockIdx.x] = ws[0] + ws[1] + ws[2] + ws[3];
}

// Stage 2: one block scans <=1024 block sums -> exclusive offsets; writes row_ptr[N]
__global__ void scan_bsums(int* __restrict__ bsum, int* __restrict__ row_ptr,
                           int nb, int N) {
    __shared__ int s[1024];
    int t = threadIdx.x;
    int v = (t < nb) ? bsum[t] : 0;
    s[t] = v;
    __syncthreads();
    for (int o = 1; o < 1024; o <<= 1) {
        int add = (t >= o) ? s[t - o] : 0;
        __syncthreads();
        s[t] += add;
        __syncthreads();
    }
    if (t < nb) bsum[t] = s[t] - v;            // exclusive
    if (t == 0) row_ptr[N] = s[1023];          // total == E
}

// Stage 3: in-block exclusive scan of cnt + block offset -> row_ptr/cursor/w/dinv
__global__ void finalize(const int* __restrict__ cnt, const int* __restrict__ bsum,
                         int* __restrict__ row_ptr, int* __restrict__ cursor,
                         float* __restrict__ w, float* __restrict__ dinv, int N) {
    __shared__ int s[256];
    int t = threadIdx.x;
    int i = blockIdx.x * blockDim.x + t;
    int c = (i < N) ? cnt[i] : 0;
    s[t] = c;
    __syncthreads();
    for (int o = 1; o < 256; o <<= 1) {
        int add = (t >= o) ? s[t - o] : 0;
        __syncthreads();
        s[t] += add;
        __syncthreads();
    }
    if (i < N) {
        int off = bsum[blockIdx.x] + s[t] - c;  // exclusive global offset
        row_ptr[i] = off;
        cursor[i]  = off;
        float deg = (float)(c + 1);             // +1 self-loop
        w[i]    = 1.0f / deg;
        dinv[i] = rsqrtf(deg);
    }
}

// Range-filtered scatter: blockIdx%8 selects a dst range (~12.5K nodes, 2.5MB of
// col). Round-robin workgroup->XCD dispatch means each col window is written by
// (mostly) one XCD -> lines complete in its L2 -> ~20MB writeback instead of 300MB.
__global__ void fill_csr(const int* __restrict__ src, const int* __restrict__ dst,
                         int* __restrict__ cursor, int* __restrict__ col,
                         int E, int range_step, int N) {
    int r = blockIdx.x & (RANGES - 1);
    int chunk = blockIdx.x >> 3;
    int nchunks = gridDim.x >> 3;
    int lo = r * range_step;
    int hi = min(lo + range_step, N);
    int stride = nchunks * blockDim.x;
    for (int e = chunk * blockDim.x + threadIdx.x; e < E; e += stride) {
        int d = __builtin_nontemporal_load(dst + e);
        if (d >= lo && d < hi) {
            int sv = __builtin_nontemporal_load(src + e);
            int p = atomicAdd(&cursor[d], 1);
            col[p] = sv;
        }
    }
}

// ---------------------------------------------------------------------------
// MLP encoder: h0 = relu(relu(x*W1+b1) @ W2 + b2); store g0 = dinv * h0
// ---------------------------------------------------------------------------
__global__ void encoder(const float* __restrict__ x, const float* __restrict__ W1,
                        const float* __restrict__ b1, const float* __restrict__ W2,
                        const float* __restrict__ b2, const float* __restrict__ dinv,
                        float* __restrict__ g0, int N) {
    int v = blockIdx.x * blockDim.x + threadIdx.x;
    if (v >= N) return;
    float xv = x[v];
    float h1[HID];
#pragma unroll
    for (int j = 0; j < HID; ++j) h1[j] = fmaxf(xv * W1[j] + b1[j], 0.0f);
    float dv = dinv[v];
#pragma unroll
    for (int j = 0; j < HID; ++j) {
        float s = b2[j];
#pragma unroll
        for (int i = 0; i < HID; ++i) s += h1[i] * W2[i * HID + j];
        g0[v * HID + j] = dv * fmaxf(s, 0.0f);
    }
}

// ---------------------------------------------------------------------------
// One APPNP round: g_out[v] = 0.9*w[v]*(sum_in g_in[src] + g_in[v]) + 0.1*g0[v]
// 16 lanes per node; group vector-loads 16 col entries, shfl-broadcasts each
// src id -> 16 independent row-gathers in flight per subgroup.
// ---------------------------------------------------------------------------
__global__ void prop(const float* __restrict__ gin, const float* __restrict__ g0,
                     const int* __restrict__ row_ptr, const int* __restrict__ col,
                     const float* __restrict__ w, float* __restrict__ gout, int N) {
    int gid = blockIdx.x * blockDim.x + threadIdx.x;
    int v = gid >> 4;
    if (v >= N) return;
    int j = threadIdx.x & 15;

    int s = row_ptr[v];
    int e = row_ptr[v + 1];

    float acc = gin[v * HID + j];            // self-loop term

    int k = s;
    for (; k + 16 <= e; k += 16) {
        int cv = __builtin_nontemporal_load(col + k + j);
#pragma unroll
        for (int i = 0; i < 16; ++i) {
            int c = __shfl(cv, i, 16);
            acc += gin[c * HID + j];
        }
    }
    int rem = e - k;
    int cvt = 0;
    if (j < rem) cvt = __builtin_nontemporal_load(col + k + j);
    for (int i = 0; i < rem; ++i) {
        int c = __shfl(cvt, i, 16);
        acc += gin[c * HID + j];
    }

    gout[v * HID + j] = 0.9f * w[v] * acc + 0.1f * g0[v * HID + j];
}

// ---------------------------------------------------------------------------
// Head: y[v] = (g_K[v]/dinv[v]) . W3 + b3
// ---------------------------------------------------------------------------
__global__ void out_head(const float* __restrict__ g, const float* __restrict__ W3,
                         const float* __restrict__ b3, const float* __restrict__ dinv,
                         float* __restrict__ y, int N) {
    int v = blockIdx.x * blockDim.x + threadIdx.x;
    if (v >= N) return;
    float s = 0.0f;
#pragma unroll
    for (int j = 0; j < HID; ++j) s += g[v * HID + j] * W3[j];
    y[v] = s / dinv[v] + b3[0];
}

extern "C" void kernel_launch(void* const* d_in, const int* in_sizes, int n_in,
                              void* d_out, int out_size, void* d_ws, size_t ws_size,
                              hipStream_t stream) {
    const float* x  = (const float*)d_in[0];
    const int* edge = (const int*)d_in[1];
    const float* W1 = (const float*)d_in[2];
    const float* b1 = (const float*)d_in[3];
    const float* W2 = (const float*)d_in[4];
    const float* b2 = (const float*)d_in[5];
    const float* W3 = (const float*)d_in[6];
    const float* b3 = (const float*)d_in[7];
    float* y = (float*)d_out;

    const int N = in_sizes[0];       // 100000
    const int E = in_sizes[1] / 2;   // 5000000
    const int* src = edge;
    const int* dst = edge + E;

    char* ws = (char*)d_ws;
    size_t off = 0;
    auto alloc = [&](size_t bytes) -> void* {
        void* p = ws + off;
        off += (bytes + 255) & ~(size_t)255;
        return p;
    };

    int*   cnt     = (int*)  alloc((size_t)N * 4);
    int*   row_ptr = (int*)  alloc((size_t)(N + 1) * 4);
    int*   cursor  = (int*)  alloc((size_t)N * 4);
    int*   col     = (int*)  alloc((size_t)E * 4);
    float* w       = (float*)alloc((size_t)N * 4);
    float* dinv    = (float*)alloc((size_t)N * 4);
    float* g0      = (float*)alloc((size_t)N * HID * 4);
    float* gB      = (float*)alloc((size_t)N * HID * 4);
    float* gC      = (float*)alloc((size_t)N * HID * 4);
    int*   bsum    = (int*)  alloc(1024 * 4);

    const int nb = (N + 255) / 256;   // 391 <= 1024

    hipMemsetAsync(cnt, 0, (size_t)N * 4, stream);

    count_deg<<<(E + 255) / 256, 256, 0, stream>>>(dst, cnt, E);
    block_reduce<<<nb, 256, 0, stream>>>(cnt, bsum, N);
    scan_bsums<<<1, 1024, 0, stream>>>(bsum, row_ptr, nb, N);
    finalize<<<nb, 256, 0, stream>>>(cnt, bsum, row_ptr, cursor, w, dinv, N);

    int range_step = (N + RANGES - 1) / RANGES;
    fill_csr<<<2048, 256, 0, stream>>>(src, dst, cursor, col, E, range_step, N);

    encoder<<<(N + 255) / 256, 256, 0, stream>>>(x, W1, b1, W2, b2, dinv, g0, N);

    const float* gin = g0;
    float* gout = gB;
    for (int k = 0; k < 10; ++k) {
        long long total = (long long)N * 16;   // 16 lanes per node
        prop<<<(int)((total + 255) / 256), 256, 0, stream>>>(gin, g0, row_ptr, col, w, gout, N);
        gin = gout;
        gout = (gout == gB) ? gC : gB;
    }

    out_head<<<(N + 255) / 256, 256, 0, stream>>>(gin, W3, b3, dinv, y, N);
}

// Round 5
// 1009.144 us; speedup vs baseline: 2.3812x; 1.0887x over previous
//
#include <hip/hip_runtime.h>
#include <hip/hip_fp16.h>
#include <math.h>

#define HID 16
#define RANGES 8

// ---------------------------------------------------------------------------
// CSR build: count in-degrees, hierarchical prefix-sum, range-filtered scatter
// ---------------------------------------------------------------------------

__global__ void count_deg(const int* __restrict__ dst, int* __restrict__ cnt, int E) {
    int e = blockIdx.x * blockDim.x + threadIdx.x;
    if (e < E) atomicAdd(&cnt[__builtin_nontemporal_load(dst + e)], 1);
}

// Stage 1: per-block (256 counts) sum -> bsum[block]
__global__ void block_reduce(const int* __restrict__ cnt, int* __restrict__ bsum, int N) {
    int i = blockIdx.x * blockDim.x + threadIdx.x;
    int v = (i < N) ? cnt[i] : 0;
#pragma unroll
    for (int o = 1; o < 64; o <<= 1) v += __shfl_xor(v, o);
    __shared__ int ws[4];
    int lane = threadIdx.x & 63;
    int wid = threadIdx.x >> 6;
    if (lane == 0) ws[wid] = v;
    __syncthreads();
    if (threadIdx.x == 0) bsum[blockIdx.x] = ws[0] + ws[1] + ws[2] + ws[3];
}

// Stage 2: one block scans <=1024 block sums -> exclusive offsets; writes row_ptr[N]
__global__ void scan_bsums(int* __restrict__ bsum, int* __restrict__ row_ptr,
                           int nb, int N) {
    __shared__ int s[1024];
    int t = threadIdx.x;
    int v = (t < nb) ? bsum[t] : 0;
    s[t] = v;
    __syncthreads();
    for (int o = 1; o < 1024; o <<= 1) {
        int add = (t >= o) ? s[t - o] : 0;
        __syncthreads();
        s[t] += add;
        __syncthreads();
    }
    if (t < nb) bsum[t] = s[t] - v;            // exclusive
    if (t == 0) row_ptr[N] = s[1023];          // total == E
}

// Stage 3: in-block exclusive scan of cnt + block offset -> row_ptr/cursor/w/dinv
// w is pre-multiplied by (1-alpha)=0.9: w9 = 0.9/deg
__global__ void finalize(const int* __restrict__ cnt, const int* __restrict__ bsum,
                         int* __restrict__ row_ptr, int* __restrict__ cursor,
                         float* __restrict__ w9, float* __restrict__ dinv, int N) {
    __shared__ int s[256];
    int t = threadIdx.x;
    int i = blockIdx.x * blockDim.x + t;
    int c = (i < N) ? cnt[i] : 0;
    s[t] = c;
    __syncthreads();
    for (int o = 1; o < 256; o <<= 1) {
        int add = (t >= o) ? s[t - o] : 0;
        __syncthreads();
        s[t] += add;
        __syncthreads();
    }
    if (i < N) {
        int off = bsum[blockIdx.x] + s[t] - c;  // exclusive global offset
        row_ptr[i] = off;
        cursor[i]  = off;
        float deg = (float)(c + 1);             // +1 self-loop
        w9[i]   = 0.9f / deg;
        dinv[i] = rsqrtf(deg);
    }
}

// Range-filtered scatter: blockIdx%8 selects a dst range; round-robin
// workgroup->XCD dispatch keeps each col window mostly in one XCD's L2.
__global__ void fill_csr(const int* __restrict__ src, const int* __restrict__ dst,
                         int* __restrict__ cursor, int* __restrict__ col,
                         int E, int range_step, int N) {
    int r = blockIdx.x & (RANGES - 1);
    int chunk = blockIdx.x >> 3;
    int nchunks = gridDim.x >> 3;
    int lo = r * range_step;
    int hi = min(lo + range_step, N);
    int stride = nchunks * blockDim.x;
    for (int e = chunk * blockDim.x + threadIdx.x; e < E; e += stride) {
        int d = __builtin_nontemporal_load(dst + e);
        if (d >= lo && d < hi) {
            int sv = __builtin_nontemporal_load(src + e);
            int p = atomicAdd(&cursor[d], 1);
            col[p] = sv;
        }
    }
}

// ---------------------------------------------------------------------------
// MLP encoder: h0 = relu(relu(x*W1+b1) @ W2 + b2)
// g0f = dinv*h0 (fp32, for the alpha term); gh0 = fp16 copy (round-1 gather src)
// ---------------------------------------------------------------------------
__global__ void encoder(const float* __restrict__ x, const float* __restrict__ W1,
                        const float* __restrict__ b1, const float* __restrict__ W2,
                        const float* __restrict__ b2, const float* __restrict__ dinv,
                        float* __restrict__ g0f, __half* __restrict__ gh0, int N) {
    int v = blockIdx.x * blockDim.x + threadIdx.x;
    if (v >= N) return;
    float xv = x[v];
    float h1[HID];
#pragma unroll
    for (int j = 0; j < HID; ++j) h1[j] = fmaxf(xv * W1[j] + b1[j], 0.0f);
    float dv = dinv[v];
#pragma unroll
    for (int j = 0; j < HID; ++j) {
        float s = b2[j];
#pragma unroll
        for (int i = 0; i < HID; ++i) s += h1[i] * W2[i * HID + j];
        float g = dv * fmaxf(s, 0.0f);
        g0f[v * HID + j] = g;
        gh0[v * HID + j] = __float2half(g);
    }
}

// ---------------------------------------------------------------------------
// One APPNP round: g_out[v] = w9[v]*(sum_in g_in[src] + g_in[v]) + 0.1*g0[v]
// g state is fp16 (3.2MB -> fully resident in every XCD's 4MB L2, so the
// random per-edge row-gathers are L2 hits). Accumulate fp32. 16 lanes/node;
// group vector-loads 16 col entries, shfl-broadcasts each src id -> 16
// independent gathers in flight per subgroup.
// ---------------------------------------------------------------------------
__global__ void prop(const __half* __restrict__ gin, const float* __restrict__ g0f,
                     const int* __restrict__ row_ptr, const int* __restrict__ col,
                     const float* __restrict__ w9, __half* __restrict__ gout, int N) {
    int gid = blockIdx.x * blockDim.x + threadIdx.x;
    int v = gid >> 4;
    if (v >= N) return;
    int j = threadIdx.x & 15;

    int s = row_ptr[v];
    int e = row_ptr[v + 1];

    float acc = __half2float(gin[v * HID + j]);   // self-loop term

    int k = s;
    for (; k + 16 <= e; k += 16) {
        int cv = __builtin_nontemporal_load(col + k + j);
#pragma unroll
        for (int i = 0; i < 16; ++i) {
            int c = __shfl(cv, i, 16);
            acc += __half2float(gin[c * HID + j]);
        }
    }
    int rem = e - k;
    int cvt = 0;
    if (j < rem) cvt = __builtin_nontemporal_load(col + k + j);
    for (int i = 0; i < rem; ++i) {
        int c = __shfl(cvt, i, 16);
        acc += __half2float(gin[c * HID + j]);
    }

    gout[v * HID + j] = __float2half(w9[v] * acc + 0.1f * g0f[v * HID + j]);
}

// ---------------------------------------------------------------------------
// Head: y[v] = (g_K[v]/dinv[v]) . W3 + b3
// ---------------------------------------------------------------------------
__global__ void out_head(const __half* __restrict__ g, const float* __restrict__ W3,
                         const float* __restrict__ b3, const float* __restrict__ dinv,
                         float* __restrict__ y, int N) {
    int v = blockIdx.x * blockDim.x + threadIdx.x;
    if (v >= N) return;
    float s = 0.0f;
#pragma unroll
    for (int j = 0; j < HID; ++j) s += __half2float(g[v * HID + j]) * W3[j];
    y[v] = s / dinv[v] + b3[0];
}

extern "C" void kernel_launch(void* const* d_in, const int* in_sizes, int n_in,
                              void* d_out, int out_size, void* d_ws, size_t ws_size,
                              hipStream_t stream) {
    const float* x  = (const float*)d_in[0];
    const int* edge = (const int*)d_in[1];
    const float* W1 = (const float*)d_in[2];
    const float* b1 = (const float*)d_in[3];
    const float* W2 = (const float*)d_in[4];
    const float* b2 = (const float*)d_in[5];
    const float* W3 = (const float*)d_in[6];
    const float* b3 = (const float*)d_in[7];
    float* y = (float*)d_out;

    const int N = in_sizes[0];       // 100000
    const int E = in_sizes[1] / 2;   // 5000000
    const int* src = edge;
    const int* dst = edge + E;

    char* ws = (char*)d_ws;
    size_t off = 0;
    auto alloc = [&](size_t bytes) -> void* {
        void* p = ws + off;
        off += (bytes + 255) & ~(size_t)255;
        return p;
    };

    int*    cnt     = (int*)   alloc((size_t)N * 4);
    int*    row_ptr = (int*)   alloc((size_t)(N + 1) * 4);
    int*    cursor  = (int*)   alloc((size_t)N * 4);
    int*    col     = (int*)   alloc((size_t)E * 4);
    float*  w9      = (float*) alloc((size_t)N * 4);
    float*  dinv    = (float*) alloc((size_t)N * 4);
    float*  g0f     = (float*) alloc((size_t)N * HID * 4);
    __half* gh0     = (__half*)alloc((size_t)N * HID * 2);
    __half* ghB     = (__half*)alloc((size_t)N * HID * 2);
    __half* ghC     = (__half*)alloc((size_t)N * HID * 2);
    int*    bsum    = (int*)   alloc(1024 * 4);

    const int nb = (N + 255) / 256;   // 391 <= 1024

    hipMemsetAsync(cnt, 0, (size_t)N * 4, stream);

    count_deg<<<(E + 255) / 256, 256, 0, stream>>>(dst, cnt, E);
    block_reduce<<<nb, 256, 0, stream>>>(cnt, bsum, N);
    scan_bsums<<<1, 1024, 0, stream>>>(bsum, row_ptr, nb, N);
    finalize<<<nb, 256, 0, stream>>>(cnt, bsum, row_ptr, cursor, w9, dinv, N);

    int range_step = (N + RANGES - 1) / RANGES;
    fill_csr<<<2048, 256, 0, stream>>>(src, dst, cursor, col, E, range_step, N);

    encoder<<<(N + 255) / 256, 256, 0, stream>>>(x, W1, b1, W2, b2, dinv, g0f, gh0, N);

    const __half* gin = gh0;
    __half* gout = ghB;
    for (int k = 0; k < 10; ++k) {
        long long total = (long long)N * 16;   // 16 lanes per node
        prop<<<(int)((total + 255) / 256), 256, 0, stream>>>(gin, g0f, row_ptr, col, w9, gout, N);
        gin = gout;
        gout = (gout == ghB) ? ghC : ghB;
    }

    out_head<<<(N + 255) / 256, 256, 0, stream>>>(gin, W3, b3, dinv, y, N);
}